// Round 4
// baseline (5133.645 us; speedup 1.0000x reference)
//
#include <hip/hip_runtime.h>
#include <hip/hip_bf16.h>

#define N_ROWS 100000
#define IN_C   128
#define OUT_C  64
#define S_SC   3
#define NNZ    1600000
#define NMAT   7

#define RPB_F  128                    // rows per bucket (LDS acc tile = 32 KB)
#define NBKT   782                    // ceil(100000/128)
#define EPB_A  4096                   // edges per hist/fill block
#define FB     391                    // ceil(NNZ/EPB_A)
#define BB_STR (NBKT + 1)

struct RowPtrs { const int* p[NMAT]; };

__device__ __forceinline__ float bf2f(__hip_bfloat16 x) { return __bfloat162float(x); }

// ---------------------------------------------------------------------------
// 1) Per-(block,bucket) histogram partials. Same edge blocking as fill_a.
//    partial[m][blk][b] = #edges in block blk with row>>7 == b. No global atomics.
// ---------------------------------------------------------------------------
__global__ __launch_bounds__(512)
void hist_fa(RowPtrs P, int* __restrict__ partial)
{
    __shared__ int h[NBKT];
    const int m = blockIdx.y, blk = blockIdx.x, t = threadIdx.x;
    for (int i = t; i < NBKT; i += 512) h[i] = 0;
    __syncthreads();

    const int4* r4 = (const int4*)P.p[m];
    const int i0 = blk * (EPB_A / 4);
    const int n4 = min(EPB_A / 4, NNZ / 4 - i0);
    for (int i = t; i < n4; i += 512) {
        const int4 v = r4[i0 + i];
        atomicAdd(&h[v.x >> 7], 1);
        atomicAdd(&h[v.y >> 7], 1);
        atomicAdd(&h[v.z >> 7], 1);
        atomicAdd(&h[v.w >> 7], 1);
    }
    __syncthreads();

    int* dst = partial + ((size_t)m * FB + blk) * NBKT;
    for (int i = t; i < NBKT; i += 512) dst[i] = h[i];
}

// ---------------------------------------------------------------------------
// 2) Column scan: bucket totals -> exclusive bucket bases (bucket_base), and
//    per-(block,bucket) running write bases (gbase_all). One block per matrix.
// ---------------------------------------------------------------------------
__global__ __launch_bounds__(256)
void colscan(const int* __restrict__ partial, int* __restrict__ gbase_all,
             int* __restrict__ bucket_base)
{
    __shared__ int tot[NBKT];
    __shared__ int ps[2][256];
    const int m = blockIdx.x, t = threadIdx.x;
    const int* pm = partial + (size_t)m * FB * NBKT;

    // A: column totals (threads sweep consecutive b -> coalesced)
    for (int k = 0; k < 4; ++k) {
        const int b = k * 256 + t;
        if (b < NBKT) {
            int s = 0;
            for (int blk = 0; blk < FB; ++blk) s += pm[(size_t)blk * NBKT + b];
            tot[b] = s;
        }
    }
    __syncthreads();

    // B: exclusive scan of tot[0..NBKT) — thread owns 4 consecutive entries
    int v[4]; int s = 0;
    for (int k = 0; k < 4; ++k) { const int b = 4 * t + k; v[k] = (b < NBKT) ? tot[b] : 0; s += v[k]; }
    ps[0][t] = s;
    __syncthreads();
    int sp = 0;
    for (int off = 1; off < 256; off <<= 1) {
        ps[1 - sp][t] = ps[sp][t] + ((t >= off) ? ps[sp][t - off] : 0);
        sp ^= 1;
        __syncthreads();
    }
    int base = (t == 0) ? 0 : ps[sp][t - 1];
    for (int k = 0; k < 4; ++k) { const int b = 4 * t + k; if (b < NBKT) { tot[b] = base; base += v[k]; } }
    __syncthreads();

    // C: per-column running base over blocks + bucket_base out
    int* gm = gbase_all + (size_t)m * FB * NBKT;
    int* bb = bucket_base + (size_t)m * BB_STR;
    for (int k = 0; k < 4; ++k) {
        const int b = k * 256 + t;
        if (b < NBKT) {
            int run = tot[b];
            bb[b] = run;
            for (int blk = 0; blk < FB; ++blk) {
                const size_t idx = (size_t)blk * NBKT + b;
                const int g = pm[idx];
                gm[idx] = run;
                run += g;
            }
        }
    }
    if (t == 0) bb[NBKT] = NNZ;
}

// ---------------------------------------------------------------------------
// 3) Bucket scatter: deterministic, zero global atomics. Each block stages its
//    4096 records grouped by bucket in LDS, then writes coalesced-ish runs to
//    its precomputed exclusive segment gbase_all[blk][b].
//    Record: x = (r_local<<17)|col, y = val bits.
// ---------------------------------------------------------------------------
__global__ __launch_bounds__(512)
void fill_a(const int* __restrict__ rows, const int* __restrict__ cols,
            const float* __restrict__ vals, const int* __restrict__ part_m,
            const int* __restrict__ gb_m, uint2* __restrict__ bkt)
{
    __shared__ int cnt[NBKT], lofs[NBKT], lcur[NBKT], gb[NBKT];   // 12.5 KB
    __shared__ uint2 stg[EPB_A];                                   // 32 KB
    __shared__ int gpos[EPB_A];                                    // 16 KB
    __shared__ int ps[2][256];                                     // 2 KB
    const int blk = blockIdx.x, t = threadIdx.x;
    const int e0 = blk * EPB_A;
    const int n  = min(EPB_A, NNZ - e0);

    for (int i = t; i < NBKT; i += 512) {
        cnt[i] = part_m[(size_t)blk * NBKT + i];
        gb[i]  = gb_m[(size_t)blk * NBKT + i];
    }
    __syncthreads();

    // local exclusive scan of cnt -> lofs/lcur
    if (t < 256) {
        int v[4]; int s = 0;
        for (int k = 0; k < 4; ++k) { const int b = 4 * t + k; v[k] = (b < NBKT) ? cnt[b] : 0; s += v[k]; }
        ps[0][t] = s;
    }
    __syncthreads();
    int sp = 0;
    for (int off = 1; off < 256; off <<= 1) {
        if (t < 256) ps[1 - sp][t] = ps[sp][t] + ((t >= off) ? ps[sp][t - off] : 0);
        sp ^= 1;
        __syncthreads();
    }
    if (t < 256) {
        int base = (t == 0) ? 0 : ps[sp][t - 1];
        for (int k = 0; k < 4; ++k) {
            const int b = 4 * t + k;
            if (b < NBKT) { lofs[b] = base; lcur[b] = base; base += cnt[b]; }
        }
    }
    __syncthreads();

    int bb[8]; unsigned hx[8], vv[8];
    #pragma unroll
    for (int k = 0; k < 8; ++k) {
        const int idx = t + k * 512;
        if (idx < n) {
            const int e = e0 + idx;
            const int r = rows[e];
            bb[k] = r >> 7;
            hx[k] = ((unsigned)(r & (RPB_F - 1)) << 17) | (unsigned)cols[e];
            vv[k] = __float_as_uint(vals[e]);
        } else bb[k] = -1;
    }
    #pragma unroll
    for (int k = 0; k < 8; ++k) {
        if (bb[k] >= 0) {
            const int p = atomicAdd(&lcur[bb[k]], 1);
            stg[p]  = make_uint2(hx[k], vv[k]);
            gpos[p] = gb[bb[k]] + (p - lofs[bb[k]]);
        }
    }
    __syncthreads();

    for (int p = t; p < n; p += 512) bkt[gpos[p]] = stg[p];
}

// ---------------------------------------------------------------------------
// 4) LDS-accumulator SPMM: block = one 128-row bucket, acc[128][64] fp32 in
//    LDS. Streams bucket records (any order) with x4 ILP; fire-and-forget
//    ds_add_f32. MODE 0: src=W fp32 -> bf16 filtered. MODE 1: src bf16,
//    *theta -> bf16 z. MODE 2: src bf16, relu -> fp32 out[:,sc,:].
// ---------------------------------------------------------------------------
template <int MODE>
__global__ __launch_bounds__(256)
void spmm_acc(const int* __restrict__ bb, const uint2* __restrict__ bkt,
              const void* __restrict__ srcv, const float* __restrict__ theta,
              __hip_bfloat16* __restrict__ dstb, float* __restrict__ dstf, int sc)
{
    __shared__ float acc[RPB_F * OUT_C];   // 32 KB
    const int b = blockIdx.x, t = threadIdx.x, lane = t & 63, wv = t >> 6;
    for (int i = t; i < RPB_F * OUT_C; i += 256) acc[i] = 0.f;
    __syncthreads();

    const int e0 = bb[b], e1 = bb[b + 1];
    const int n  = e1 - e0, cs = (n + 3) >> 2;
    int e = e0 + wv * cs;
    const int ee = min(e + cs, e1);
    const float* W          = (const float*)srcv;
    const __hip_bfloat16* S = (const __hip_bfloat16*)srcv;

    for (; e + 3 < ee; e += 4) {
        const uint2 q0 = bkt[e], q1 = bkt[e + 1], q2 = bkt[e + 2], q3 = bkt[e + 3];
        float f0, f1, f2, f3;
        if (MODE == 0) {
            f0 = W[(q0.x & 0x1FFFFu) * OUT_C + lane];
            f1 = W[(q1.x & 0x1FFFFu) * OUT_C + lane];
            f2 = W[(q2.x & 0x1FFFFu) * OUT_C + lane];
            f3 = W[(q3.x & 0x1FFFFu) * OUT_C + lane];
        } else {
            f0 = bf2f(S[(q0.x & 0x1FFFFu) * OUT_C + lane]);
            f1 = bf2f(S[(q1.x & 0x1FFFFu) * OUT_C + lane]);
            f2 = bf2f(S[(q2.x & 0x1FFFFu) * OUT_C + lane]);
            f3 = bf2f(S[(q3.x & 0x1FFFFu) * OUT_C + lane]);
        }
        atomicAdd(&acc[(q0.x >> 17) * OUT_C + lane], __uint_as_float(q0.y) * f0);
        atomicAdd(&acc[(q1.x >> 17) * OUT_C + lane], __uint_as_float(q1.y) * f1);
        atomicAdd(&acc[(q2.x >> 17) * OUT_C + lane], __uint_as_float(q2.y) * f2);
        atomicAdd(&acc[(q3.x >> 17) * OUT_C + lane], __uint_as_float(q3.y) * f3);
    }
    for (; e < ee; ++e) {
        const uint2 q = bkt[e];
        const float f = (MODE == 0) ? W[(q.x & 0x1FFFFu) * OUT_C + lane]
                                    : bf2f(S[(q.x & 0x1FFFFu) * OUT_C + lane]);
        atomicAdd(&acc[(q.x >> 17) * OUT_C + lane], __uint_as_float(q.y) * f);
    }
    __syncthreads();

    const int r0 = b * RPB_F;
    const int nr = min(RPB_F, N_ROWS - r0);
    for (int i = t; i < nr * OUT_C; i += 256) {
        const int row = i >> 6, c = i & 63;
        const float a = acc[i];
        if (MODE == 0)
            dstb[(size_t)(r0 + row) * OUT_C + c] = __float2bfloat16(a);
        else if (MODE == 1)
            dstb[(size_t)(r0 + row) * OUT_C + c] = __float2bfloat16(theta[r0 + row] * a);
        else
            dstf[((size_t)(r0 + row) * S_SC + sc) * OUT_C + c] = (a > 0.f) ? a : 0.f;
    }
}

extern "C" void kernel_launch(void* const* d_in, const int* in_sizes, int n_in,
                              void* d_out, int out_size, void* d_ws, size_t ws_size,
                              hipStream_t stream)
{
    const int*   phi_idx  = (const int*)d_in[0];
    const float* phi_val  = (const float*)d_in[1];
    const int*   pinv_idx = (const int*)d_in[2];
    const float* pinv_val = (const float*)d_in[3];
    const int*   fidx     = (const int*)d_in[4];
    const float* fval     = (const float*)d_in[5];
    const float* W        = (const float*)d_in[6];
    const float* theta    = (const float*)d_in[7];
    float*       out      = (float*)d_out;          // (N,S,64) fp32

    // ---- workspace (≈55.7 MB; 76.8 MB proven) ----
    __hip_bfloat16* filtered = (__hip_bfloat16*)d_ws;                  // 12.8 MB
    __hip_bfloat16* z        = filtered + (size_t)N_ROWS * OUT_C;      // 12.8 MB
    uint2* bkt        = (uint2*)(z + (size_t)N_ROWS * OUT_C);          // 12.8 MB
    int*   partial    = (int*)(bkt + NNZ);                             // 8.56 MB
    int*   gbase_all  = partial + (size_t)NMAT * FB * NBKT;            // 8.56 MB
    int*   bucket_base = gbase_all + (size_t)NMAT * FB * NBKT;         // 21.9 KB

    // matrix order: 0=F, per scale i: 1+2i=PhiInv_i, 2+2i=Phi_i
    RowPtrs P;
    P.p[0] = fidx;
    for (int i = 0; i < S_SC; ++i) {
        P.p[1 + 2 * i] = pinv_idx + (size_t)(2 * i) * NNZ;
        P.p[2 + 2 * i] = phi_idx  + (size_t)(2 * i) * NNZ;
    }

    // ---- metadata: bucket partials + column scan (no global atomics) ----
    hist_fa<<<dim3(FB, NMAT), 512, 0, stream>>>(P, partial);
    colscan<<<NMAT, 256, 0, stream>>>(partial, gbase_all, bucket_base);

    // ---- m=0: filtered = bf16(F @ W) ----
    fill_a<<<FB, 512, 0, stream>>>(fidx, fidx + NNZ, fval,
                                   partial, gbase_all, bkt);
    spmm_acc<0><<<NBKT, 256, 0, stream>>>(bucket_base, bkt, W, nullptr,
                                          filtered, nullptr, 0);

    for (int i = 0; i < S_SC; ++i) {
        const int m1 = 1 + 2 * i, m2 = 2 + 2 * i;
        const int*   zr = pinv_idx + (size_t)(2 * i) * NNZ;
        const int*   zc = pinv_idx + (size_t)(2 * i + 1) * NNZ;
        const float* zv = pinv_val + (size_t)i * NNZ;
        const int*   orr = phi_idx + (size_t)(2 * i) * NNZ;
        const int*   oc = phi_idx  + (size_t)(2 * i + 1) * NNZ;
        const float* ov = phi_val  + (size_t)i * NNZ;

        // z = bf16(theta ⊙ (PhiInv_i @ filtered))
        fill_a<<<FB, 512, 0, stream>>>(zr, zc, zv,
                                       partial   + (size_t)m1 * FB * NBKT,
                                       gbase_all + (size_t)m1 * FB * NBKT, bkt);
        spmm_acc<1><<<NBKT, 256, 0, stream>>>(bucket_base + (size_t)m1 * BB_STR,
                                              bkt, filtered, theta, z, nullptr, 0);

        // out[:, i, :] = relu(Phi_i @ z)
        fill_a<<<FB, 512, 0, stream>>>(orr, oc, ov,
                                       partial   + (size_t)m2 * FB * NBKT,
                                       gbase_all + (size_t)m2 * FB * NBKT, bkt);
        spmm_acc<2><<<NBKT, 256, 0, stream>>>(bucket_base + (size_t)m2 * BB_STR,
                                              bkt, z, nullptr, nullptr, out, i);
    }
}

// Round 5
// 1192.198 us; speedup vs baseline: 4.3060x; 4.3060x over previous
//
#include <hip/hip_runtime.h>
#include <hip/hip_bf16.h>

#define N_ROWS 100000
#define IN_C   128
#define OUT_C  64
#define S_SC   3
#define NNZ    1600000
#define NMAT   7

#define NCH    16            // hist chunk-copies (parallelism only)
#define HROWS  (N_ROWS / 2)  // u16-pair words per copy

#define SEG       512
#define BLKS_SCAN 196   // 196*512 = 100352 >= 100000

#define NSEG   (NNZ / 256)   // 6250 256-edge segments
#define RPB    25000         // rows per histogram bin
#define NBIN_H 4             // 4*25000 = 100000 exact

#define RPB_F  256                           // rows per fill bucket (2^8)
#define NBKT   391                           // ceil(100000/256)
#define EPB_A  2048                          // edges per pass-A block
#define BLKS_A ((NNZ + EPB_A - 1) / EPB_A)   // 782
#define RS_STR (N_ROWS + 1)                  // row_start stride (CSR-style)

struct RowPtrs { const int* p[NMAT]; };

__device__ __forceinline__ float bf2f(__hip_bfloat16 x) { return __bfloat162float(x); }
__device__ __forceinline__ unsigned rdlane(unsigned v, int l) {
    return (unsigned)__builtin_amdgcn_readlane((int)v, l);
}

// ---------------------------------------------------------------------------
// 1) Binned histogram, zero global atomics. 16 chunk-copies, u16 counts
//    packed as row-pairs: counts16[copy][row/2] u32. Same 22.4MB footprint.
// ---------------------------------------------------------------------------
__global__ __launch_bounds__(512)
void hist_binned(RowPtrs P, unsigned* __restrict__ counts16)
{
    __shared__ unsigned cnt[RPB / 2];          // 25000 u16 packed (50 KB)
    const int m    = blockIdx.y;
    const int c    = blockIdx.x & (NCH - 1);
    const int bin0 = (blockIdx.x >> 4) * RPB;
    const int t    = threadIdx.x;

    for (int i = t; i < RPB / 2; i += 512) cnt[i] = 0;
    __syncthreads();

    const int* rows = P.p[m];
    const int wv = t >> 6;
    const int ln = t & 63;

    for (int sg = c + NCH * wv; sg < NSEG; sg += NCH * 8) {
        const int4 v = ((const int4*)rows)[sg * 64 + ln];
        unsigned i0 = (unsigned)(v.x - bin0);
        unsigned i1 = (unsigned)(v.y - bin0);
        unsigned i2 = (unsigned)(v.z - bin0);
        unsigned i3 = (unsigned)(v.w - bin0);
        if (i0 < RPB) atomicAdd(&cnt[i0 >> 1], 1u << ((i0 & 1) * 16));
        if (i1 < RPB) atomicAdd(&cnt[i1 >> 1], 1u << ((i1 & 1) * 16));
        if (i2 < RPB) atomicAdd(&cnt[i2 >> 1], 1u << ((i2 & 1) * 16));
        if (i3 < RPB) atomicAdd(&cnt[i3 >> 1], 1u << ((i3 & 1) * 16));
    }
    __syncthreads();

    unsigned* dst = counts16 + ((size_t)m * NCH + c) * HROWS + (bin0 >> 1);
    for (int i = t; i < RPB / 2; i += 512) dst[i] = cnt[i];
}

// ---------------------------------------------------------------------------
// 2a) Per-512-row block scan of totals (sum over 16 u16 copies) + block sums
// ---------------------------------------------------------------------------
__global__ __launch_bounds__(256)
void scan_l1(const unsigned* __restrict__ counts16, int* __restrict__ rs,
             int* __restrict__ bsum)
{
    __shared__ int buf[2][SEG];
    const int m   = blockIdx.y;
    const int blk = blockIdx.x;
    const int t   = threadIdx.x;
    const unsigned* cnt = counts16 + (size_t)m * NCH * HROWS;

    for (int k = t; k < SEG; k += 256) {
        const int g = blk * SEG + k;
        int tot = 0;
        if (g < N_ROWS) {
            const int wi = g >> 1, sh = (g & 1) * 16;
            for (int c = 0; c < NCH; ++c)
                tot += (int)((cnt[(size_t)c * HROWS + wi] >> sh) & 0xffffu);
        }
        buf[0][k] = tot;
    }
    __syncthreads();

    int src = 0;
    for (int off = 1; off < SEG; off <<= 1) {
        for (int k = t; k < SEG; k += 256) {
            int v = buf[src][k];
            if (k >= off) v += buf[src][k - off];
            buf[1 - src][k] = v;
        }
        src ^= 1;
        __syncthreads();
    }
    for (int k = t; k < SEG; k += 256) {
        const int g = blk * SEG + k;
        if (g < N_ROWS)
            rs[(size_t)m * RS_STR + g] = (k == 0) ? 0 : buf[src][k - 1];
    }
    if (t == 0) bsum[m * 256 + blk] = buf[src][SEG - 1];
}

// ---------------------------------------------------------------------------
// 2b) Exclusive scan of block sums; one block per matrix
// ---------------------------------------------------------------------------
__global__ __launch_bounds__(256)
void scan_l2(int* __restrict__ bsum)
{
    __shared__ int buf[2][256];
    const int t = threadIdx.x;
    int* b = bsum + blockIdx.x * 256;
    buf[0][t] = (t < BLKS_SCAN) ? b[t] : 0;
    __syncthreads();
    int src = 0;
    for (int off = 1; off < 256; off <<= 1) {
        int v = buf[src][t];
        if (t >= off) v += buf[src][t - off];
        buf[1 - src][t] = v;
        src ^= 1;
        __syncthreads();
    }
    if (t < BLKS_SCAN) b[t] = (t == 0) ? 0 : buf[src][t - 1];
}

// ---------------------------------------------------------------------------
// 2c) Finalize: absolute row starts; bucket cursors; terminal NNZ sentinel
// ---------------------------------------------------------------------------
__global__ __launch_bounds__(256)
void finalize(const int* __restrict__ bsum, int* __restrict__ rs,
              int* __restrict__ bucket_cur)
{
    const int i = blockIdx.x * 256 + threadIdx.x;
    if (i >= NMAT * N_ROWS) return;
    const int m = i / N_ROWS;
    const int r = i - m * N_ROWS;
    const size_t ri = (size_t)m * RS_STR + r;
    const int base = rs[ri] + bsum[m * 256 + r / SEG];
    rs[ri] = base;
    if ((r & (RPB_F - 1)) == 0) bucket_cur[m * NBKT + (r >> 8)] = base;
    if (r == 0) rs[(size_t)m * RS_STR + N_ROWS] = NNZ;
}

// ---------------------------------------------------------------------------
// 3a) Pass A: bucket scatter. LDS histogram + block-granular global
//     reservation (391 atomics/block) + LDS reorder -> coalesced runs.
//     Record: hi = (r_local<<17)|col, lo = val bits.
// ---------------------------------------------------------------------------
__global__ __launch_bounds__(256)
void fill_a(const int* __restrict__ rows, const int* __restrict__ cols,
            const float* __restrict__ vals, int* __restrict__ bcur,
            uint2* __restrict__ bkt)
{
    __shared__ int cnt[NBKT], lofs[NBKT], lcur[NBKT], gbase[NBKT];  // 6.3 KB
    __shared__ uint2 stg[EPB_A];                                    // 16 KB
    __shared__ int gpos[EPB_A];                                     // 8 KB
    __shared__ int ps[2][256];                                      // 2 KB
    const int t  = threadIdx.x;
    const int e0 = blockIdx.x * EPB_A;
    const int n  = min(EPB_A, NNZ - e0);

    for (int b = t; b < NBKT; b += 256) cnt[b] = 0;
    __syncthreads();

    int rr[8], cc[8], bb[8]; unsigned vv[8];
    #pragma unroll
    for (int k = 0; k < 8; ++k) {
        const int idx = t + k * 256;
        if (idx < n) {
            const int e = e0 + idx;
            rr[k] = rows[e];
            cc[k] = cols[e];
            vv[k] = __float_as_uint(vals[e]);
            bb[k] = rr[k] >> 8;
            atomicAdd(&cnt[bb[k]], 1);
        } else bb[k] = -1;
    }
    __syncthreads();

    // local exclusive scan of cnt[0..NBKT): thread owns 4 consecutive entries
    {
        int v[4]; int s = 0;
        #pragma unroll
        for (int k = 0; k < 4; ++k) {
            const int b = 4 * t + k;
            v[k] = (b < NBKT) ? cnt[b] : 0; s += v[k];
        }
        ps[0][t] = s;
        __syncthreads();
        int sp = 0;
        for (int off = 1; off < 256; off <<= 1) {
            ps[1 - sp][t] = ps[sp][t] + ((t >= off) ? ps[sp][t - off] : 0);
            sp ^= 1;
            __syncthreads();
        }
        int base = (t == 0) ? 0 : ps[sp][t - 1];
        #pragma unroll
        for (int k = 0; k < 4; ++k) {
            const int b = 4 * t + k;
            if (b < NBKT) { lofs[b] = base; lcur[b] = base; base += v[k]; }
        }
    }
    __syncthreads();

    for (int b = t; b < NBKT; b += 256)
        gbase[b] = atomicAdd(&bcur[b], cnt[b]);
    __syncthreads();

    #pragma unroll
    for (int k = 0; k < 8; ++k) {
        if (bb[k] >= 0) {
            const int p = atomicAdd(&lcur[bb[k]], 1);
            stg[p]  = make_uint2(((unsigned)(rr[k] & (RPB_F - 1)) << 17) |
                                 (unsigned)cc[k], vv[k]);
            gpos[p] = gbase[bb[k]] + (p - lofs[bb[k]]);
        }
    }
    __syncthreads();

    for (int p = t; p < n; p += 256) bkt[gpos[p]] = stg[p];
}

// ---------------------------------------------------------------------------
// 3b) Pass B: per-bucket fill with private LDS cursors. Coalesced reads,
//     scatter writes confined to an L2-resident ~32KB window.
// ---------------------------------------------------------------------------
__global__ __launch_bounds__(256)
void fill_b(const int* __restrict__ rs, const uint2* __restrict__ bkt,
            uint2* __restrict__ scv)
{
    __shared__ int cur[RPB_F];
    const int b  = blockIdx.x;
    const int r0 = b << 8;
    const int nr = min(RPB_F, N_ROWS - r0);
    const int t  = threadIdx.x;

    for (int i = t; i < nr; i += 256) cur[i] = rs[r0 + i];
    __syncthreads();

    const int e0 = rs[r0];
    const int e1 = rs[min(r0 + RPB_F, N_ROWS)];
    for (int e = e0 + t; e < e1; e += 256) {
        const uint2 rec = bkt[e];
        const int rl = (int)(rec.x >> 17);
        const int p  = atomicAdd(&cur[rl], 1);
        scv[p] = make_uint2(rec.x & 0x1FFFFu, rec.y);
    }
}

// ---------------------------------------------------------------------------
// 4a) Gather-SPMM vs LDS W. Row-PAIR processing: one coalesced lane-parallel
//     staging load of both rows' records (<=64), v_readlane broadcast, A/B
//     interleaved for 2-deep MLP.  filtered[r] = bf16(sum v * W[c])
// ---------------------------------------------------------------------------
__global__ __launch_bounds__(256)
void gather_W(const int* __restrict__ rs, const uint2* __restrict__ scv,
              const float* __restrict__ W, __hip_bfloat16* __restrict__ dst)
{
    __shared__ float Wl[IN_C * OUT_C];
    for (int i = threadIdx.x; i < IN_C * OUT_C; i += blockDim.x) Wl[i] = W[i];
    __syncthreads();

    const int lane = threadIdx.x & 63;
    const int wave = blockIdx.x * 4 + (threadIdx.x >> 6);
    const int nw   = gridDim.x * 4;

    for (int p = wave; p < N_ROWS / 2; p += nw) {
        const int rA = 2 * p;
        const int sA = rs[rA], tA = rs[rA + 1], tB = rs[rA + 2];
        const int lenA = tA - sA, lenB = tB - tA, len = tB - sA;
        float aA = 0.f, aB = 0.f;
        if (len <= 64) {
            uint2 q = make_uint2(0u, 0u);
            if (lane < len) q = scv[sA + lane];
            const int mx = (lenA > lenB) ? lenA : lenB;
            for (int k = 0; k < mx; ++k) {
                if (k < lenA) {
                    const unsigned c = rdlane(q.x, k);
                    const unsigned v = rdlane(q.y, k);
                    aA += __uint_as_float(v) * Wl[c * OUT_C + lane];
                }
                if (k < lenB) {
                    const unsigned c = rdlane(q.x, lenA + k);
                    const unsigned v = rdlane(q.y, lenA + k);
                    aB += __uint_as_float(v) * Wl[c * OUT_C + lane];
                }
            }
        } else {
            for (int j = sA; j < tA; ++j) {
                const uint2 q = scv[j];
                aA += __uint_as_float(q.y) * Wl[q.x * OUT_C + lane];
            }
            for (int j = tA; j < tB; ++j) {
                const uint2 q = scv[j];
                aB += __uint_as_float(q.y) * Wl[q.x * OUT_C + lane];
            }
        }
        dst[(size_t)rA * OUT_C + lane]       = __float2bfloat16(aA);
        dst[(size_t)(rA + 1) * OUT_C + lane] = __float2bfloat16(aB);
    }
}

// ---------------------------------------------------------------------------
// 4b) Gather-SPMM from bf16 src, same row-pair staging.
// MODE 1: dst[r] = bf16(theta[r] * sum v*src[c])
// MODE 2: out[(r*3+scale)] = relu(sum v*src[c])   (fp32)
// ---------------------------------------------------------------------------
template <int MODE>
__global__ __launch_bounds__(256)
void gather_mat(const int* __restrict__ rs, const uint2* __restrict__ scv,
                const __hip_bfloat16* __restrict__ src,
                const float* __restrict__ theta,
                __hip_bfloat16* __restrict__ dstb,
                float* __restrict__ dstf, int scale)
{
    const int lane = threadIdx.x & 63;
    const int wave = blockIdx.x * 4 + (threadIdx.x >> 6);
    const int nw   = gridDim.x * 4;

    for (int p = wave; p < N_ROWS / 2; p += nw) {
        const int rA = 2 * p;
        const int sA = rs[rA], tA = rs[rA + 1], tB = rs[rA + 2];
        const int lenA = tA - sA, lenB = tB - tA, len = tB - sA;
        float aA = 0.f, aB = 0.f;
        if (len <= 64) {
            uint2 q = make_uint2(0u, 0u);
            if (lane < len) q = scv[sA + lane];
            const int mx = (lenA > lenB) ? lenA : lenB;
            for (int k = 0; k < mx; ++k) {
                if (k < lenA) {
                    const unsigned c = rdlane(q.x, k);
                    const unsigned v = rdlane(q.y, k);
                    aA += __uint_as_float(v) * bf2f(src[(size_t)c * OUT_C + lane]);
                }
                if (k < lenB) {
                    const unsigned c = rdlane(q.x, lenA + k);
                    const unsigned v = rdlane(q.y, lenA + k);
                    aB += __uint_as_float(v) * bf2f(src[(size_t)c * OUT_C + lane]);
                }
            }
        } else {
            for (int j = sA; j < tA; ++j) {
                const uint2 q = scv[j];
                aA += __uint_as_float(q.y) * bf2f(src[(size_t)q.x * OUT_C + lane]);
            }
            for (int j = tA; j < tB; ++j) {
                const uint2 q = scv[j];
                aB += __uint_as_float(q.y) * bf2f(src[(size_t)q.x * OUT_C + lane]);
            }
        }
        if (MODE == 1) {
            dstb[(size_t)rA * OUT_C + lane]       = __float2bfloat16(theta[rA] * aA);
            dstb[(size_t)(rA + 1) * OUT_C + lane] = __float2bfloat16(theta[rA + 1] * aB);
        } else {
            dstf[((size_t)rA * S_SC + scale) * OUT_C + lane]       = aA > 0.f ? aA : 0.f;
            dstf[((size_t)(rA + 1) * S_SC + scale) * OUT_C + lane] = aB > 0.f ? aB : 0.f;
        }
    }
}

extern "C" void kernel_launch(void* const* d_in, const int* in_sizes, int n_in,
                              void* d_out, int out_size, void* d_ws, size_t ws_size,
                              hipStream_t stream)
{
    const int*   phi_idx  = (const int*)d_in[0];
    const float* phi_val  = (const float*)d_in[1];
    const int*   pinv_idx = (const int*)d_in[2];
    const float* pinv_val = (const float*)d_in[3];
    const int*   fidx     = (const int*)d_in[4];
    const float* fval     = (const float*)d_in[5];
    const float* W        = (const float*)d_in[6];
    const float* theta    = (const float*)d_in[7];
    float*       out      = (float*)d_out;          // (N,S,64) fp32

    // ---- workspace (≈76.4 MB; 76.8 MB proven) ----
    __hip_bfloat16* filtered = (__hip_bfloat16*)d_ws;                  // 12.8 MB
    __hip_bfloat16* z        = filtered + (size_t)N_ROWS * OUT_C;      // 12.8 MB
    uint2* bkt = (uint2*)(z + (size_t)N_ROWS * OUT_C);                 // 12.8 MB
    uint2* scv = bkt + NNZ;                                            // 12.8 MB
    unsigned* counts16 = (unsigned*)(scv + NNZ);                       // 22.4 MB
    int*   rs          = (int*)(counts16 + (size_t)NMAT * NCH * HROWS);// 2.8 MB
    int*   bsum        = rs + (size_t)NMAT * RS_STR;                   // 7 KB
    int*   bucket_cur  = bsum + NMAT * 256;                            // 11 KB

    // matrix order: 0=F, per scale i: 1+2i=PhiInv_i, 2+2i=Phi_i
    RowPtrs P;
    P.p[0] = fidx;
    for (int i = 0; i < S_SC; ++i) {
        P.p[1 + 2 * i] = pinv_idx + (size_t)(2 * i) * NNZ;
        P.p[2 + 2 * i] = phi_idx  + (size_t)(2 * i) * NNZ;
    }

    // ---- batched CSR metadata for all 7 matrices ----
    hist_binned<<<dim3(NCH * NBIN_H, NMAT), 512, 0, stream>>>(P, counts16);
    scan_l1<<<dim3(BLKS_SCAN, NMAT), 256, 0, stream>>>(counts16, rs, bsum);
    scan_l2<<<NMAT, 256, 0, stream>>>(bsum);
    finalize<<<(NMAT * N_ROWS + 255) / 256, 256, 0, stream>>>(bsum, rs, bucket_cur);

    // ---- m=0: filtered = bf16(F @ W) ----
    fill_a<<<BLKS_A, 256, 0, stream>>>(fidx, fidx + NNZ, fval, bucket_cur, bkt);
    fill_b<<<NBKT, 256, 0, stream>>>(rs, bkt, scv);
    gather_W<<<4096, 256, 0, stream>>>(rs, scv, W, filtered);

    for (int i = 0; i < S_SC; ++i) {
        const int m1 = 1 + 2 * i, m2 = 2 + 2 * i;
        const int*   zc = pinv_idx + (size_t)(2 * i + 1) * NNZ;
        const float* zv = pinv_val + (size_t)i * NNZ;
        const int*   oc = phi_idx  + (size_t)(2 * i + 1) * NNZ;
        const float* ov = phi_val  + (size_t)i * NNZ;

        // z = bf16(theta ⊙ (PhiInv_i @ filtered))
        fill_a<<<BLKS_A, 256, 0, stream>>>(P.p[m1], zc, zv,
                                           bucket_cur + m1 * NBKT, bkt);
        fill_b<<<NBKT, 256, 0, stream>>>(rs + (size_t)m1 * RS_STR, bkt, scv);
        gather_mat<1><<<4096, 256, 0, stream>>>(rs + (size_t)m1 * RS_STR, scv,
                                                filtered, theta, z, nullptr, 0);

        // out[:, i, :] = relu(Phi_i @ z)
        fill_a<<<BLKS_A, 256, 0, stream>>>(P.p[m2], oc, ov,
                                           bucket_cur + m2 * NBKT, bkt);
        fill_b<<<NBKT, 256, 0, stream>>>(rs + (size_t)m2 * RS_STR, bkt, scv);
        gather_mat<2><<<4096, 256, 0, stream>>>(rs + (size_t)m2 * RS_STR, scv,
                                                z, nullptr, nullptr, out, i);
    }
}

// Round 6
// 1020.778 us; speedup vs baseline: 5.0291x; 1.1679x over previous
//
#include <hip/hip_runtime.h>
#include <hip/hip_bf16.h>

#define N_ROWS 100000
#define IN_C   128
#define OUT_C  64
#define S_SC   3
#define NNZ    1600000
#define NMAT   7

#define NCH    16            // hist chunk-copies (parallelism only)
#define HROWS  (N_ROWS / 2)  // u16-pair words per copy

#define SEG       512
#define BLKS_SCAN 196   // 196*512 = 100352 >= 100000

#define NSEG   (NNZ / 256)   // 6250 256-edge segments
#define RPB    25000         // rows per histogram bin
#define NBIN_H 4             // 4*25000 = 100000 exact

#define RPB_F  1024                          // rows per fill bucket (2^10)
#define NBKT   98                            // ceil(100000/1024)
#define EPB_A  2048                          // edges per pass-A block
#define BLKS_A ((NNZ + EPB_A - 1) / EPB_A)   // 782
#define RS_STR (N_ROWS + 1)                  // row_start stride (CSR-style)

struct RowPtrs { const int* p[NMAT]; };

__device__ __forceinline__ float bf2f(__hip_bfloat16 x) { return __bfloat162float(x); }

// ---------------------------------------------------------------------------
// 1) Binned histogram, zero global atomics. 16 chunk-copies, u16 counts
//    packed as row-pairs: counts16[copy][row/2] u32.
// ---------------------------------------------------------------------------
__global__ __launch_bounds__(512)
void hist_binned(RowPtrs P, unsigned* __restrict__ counts16)
{
    __shared__ unsigned cnt[RPB / 2];          // 25000 u16 packed (50 KB)
    const int m    = blockIdx.y;
    const int c    = blockIdx.x & (NCH - 1);
    const int bin0 = (blockIdx.x >> 4) * RPB;
    const int t    = threadIdx.x;

    for (int i = t; i < RPB / 2; i += 512) cnt[i] = 0;
    __syncthreads();

    const int* rows = P.p[m];
    const int wv = t >> 6;
    const int ln = t & 63;

    for (int sg = c + NCH * wv; sg < NSEG; sg += NCH * 8) {
        const int4 v = ((const int4*)rows)[sg * 64 + ln];
        unsigned i0 = (unsigned)(v.x - bin0);
        unsigned i1 = (unsigned)(v.y - bin0);
        unsigned i2 = (unsigned)(v.z - bin0);
        unsigned i3 = (unsigned)(v.w - bin0);
        if (i0 < RPB) atomicAdd(&cnt[i0 >> 1], 1u << ((i0 & 1) * 16));
        if (i1 < RPB) atomicAdd(&cnt[i1 >> 1], 1u << ((i1 & 1) * 16));
        if (i2 < RPB) atomicAdd(&cnt[i2 >> 1], 1u << ((i2 & 1) * 16));
        if (i3 < RPB) atomicAdd(&cnt[i3 >> 1], 1u << ((i3 & 1) * 16));
    }
    __syncthreads();

    unsigned* dst = counts16 + ((size_t)m * NCH + c) * HROWS + (bin0 >> 1);
    for (int i = t; i < RPB / 2; i += 512) dst[i] = cnt[i];
}

// ---------------------------------------------------------------------------
// 2a) Per-512-row block scan of totals (sum over 16 u16 copies) + block sums
// ---------------------------------------------------------------------------
__global__ __launch_bounds__(256)
void scan_l1(const unsigned* __restrict__ counts16, int* __restrict__ rs,
             int* __restrict__ bsum)
{
    __shared__ int buf[2][SEG];
    const int m   = blockIdx.y;
    const int blk = blockIdx.x;
    const int t   = threadIdx.x;
    const unsigned* cnt = counts16 + (size_t)m * NCH * HROWS;

    for (int k = t; k < SEG; k += 256) {
        const int g = blk * SEG + k;
        int tot = 0;
        if (g < N_ROWS) {
            const int wi = g >> 1, sh = (g & 1) * 16;
            for (int c = 0; c < NCH; ++c)
                tot += (int)((cnt[(size_t)c * HROWS + wi] >> sh) & 0xffffu);
        }
        buf[0][k] = tot;
    }
    __syncthreads();

    int src = 0;
    for (int off = 1; off < SEG; off <<= 1) {
        for (int k = t; k < SEG; k += 256) {
            int v = buf[src][k];
            if (k >= off) v += buf[src][k - off];
            buf[1 - src][k] = v;
        }
        src ^= 1;
        __syncthreads();
    }
    for (int k = t; k < SEG; k += 256) {
        const int g = blk * SEG + k;
        if (g < N_ROWS)
            rs[(size_t)m * RS_STR + g] = (k == 0) ? 0 : buf[src][k - 1];
    }
    if (t == 0) bsum[m * 256 + blk] = buf[src][SEG - 1];
}

// ---------------------------------------------------------------------------
// 2b) Exclusive scan of block sums; one block per matrix
// ---------------------------------------------------------------------------
__global__ __launch_bounds__(256)
void scan_l2(int* __restrict__ bsum)
{
    __shared__ int buf[2][256];
    const int t = threadIdx.x;
    int* b = bsum + blockIdx.x * 256;
    buf[0][t] = (t < BLKS_SCAN) ? b[t] : 0;
    __syncthreads();
    int src = 0;
    for (int off = 1; off < 256; off <<= 1) {
        int v = buf[src][t];
        if (t >= off) v += buf[src][t - off];
        buf[1 - src][t] = v;
        src ^= 1;
        __syncthreads();
    }
    if (t < BLKS_SCAN) b[t] = (t == 0) ? 0 : buf[src][t - 1];
}

// ---------------------------------------------------------------------------
// 2c) Finalize: absolute row starts; bucket cursors; terminal NNZ sentinel
// ---------------------------------------------------------------------------
__global__ __launch_bounds__(256)
void finalize(const int* __restrict__ bsum, int* __restrict__ rs,
              int* __restrict__ bucket_cur)
{
    const int i = blockIdx.x * 256 + threadIdx.x;
    if (i >= NMAT * N_ROWS) return;
    const int m = i / N_ROWS;
    const int r = i - m * N_ROWS;
    const size_t ri = (size_t)m * RS_STR + r;
    const int base = rs[ri] + bsum[m * 256 + r / SEG];
    rs[ri] = base;
    if ((r & (RPB_F - 1)) == 0) bucket_cur[m * NBKT + (r >> 10)] = base;
    if (r == 0) rs[(size_t)m * RS_STR + N_ROWS] = NNZ;
}

// ---------------------------------------------------------------------------
// 3a) Pass A: bucket scatter. LDS histogram + block-granular global
//     reservation (98 atomics/block) + LDS reorder -> coalesced runs.
//     Record: hi = (r_local<<17)|col, lo = val bits.
// ---------------------------------------------------------------------------
__global__ __launch_bounds__(256)
void fill_a(const int* __restrict__ rows, const int* __restrict__ cols,
            const float* __restrict__ vals, int* __restrict__ bcur,
            uint2* __restrict__ bkt)
{
    __shared__ int cnt[NBKT], lofs[NBKT], lcur[NBKT], gbase[NBKT];
    __shared__ uint2 stg[EPB_A];
    __shared__ int gpos[EPB_A];
    const int t  = threadIdx.x;
    const int e0 = blockIdx.x * EPB_A;
    const int n  = min(EPB_A, NNZ - e0);

    for (int b = t; b < NBKT; b += 256) cnt[b] = 0;
    __syncthreads();

    int rr[8], cc[8], bb[8]; unsigned vv[8];
    #pragma unroll
    for (int k = 0; k < 8; ++k) {
        const int idx = t + k * 256;
        if (idx < n) {
            const int e = e0 + idx;
            rr[k] = rows[e];
            cc[k] = cols[e];
            vv[k] = __float_as_uint(vals[e]);
            bb[k] = rr[k] >> 10;
            atomicAdd(&cnt[bb[k]], 1);
        } else bb[k] = -1;
    }
    __syncthreads();

    if (t == 0) {
        int run = 0;
        for (int b = 0; b < NBKT; ++b) { lofs[b] = run; run += cnt[b]; }
    }
    __syncthreads();
    if (t < NBKT) {
        gbase[t] = atomicAdd(&bcur[t], cnt[t]);
        lcur[t]  = lofs[t];
    }
    __syncthreads();

    #pragma unroll
    for (int k = 0; k < 8; ++k) {
        if (bb[k] >= 0) {
            const int p = atomicAdd(&lcur[bb[k]], 1);
            stg[p]  = make_uint2(((unsigned)(rr[k] & (RPB_F - 1)) << 17) |
                                 (unsigned)cc[k], vv[k]);
            gpos[p] = gbase[bb[k]] + (p - lofs[bb[k]]);
        }
    }
    __syncthreads();

    for (int p = t; p < n; p += 256)
        bkt[gpos[p]] = stg[p];
}

// ---------------------------------------------------------------------------
// 3b) Pass B: per-bucket fill with private LDS cursors. Coalesced reads,
//     scatter writes confined to an L2-resident ~130KB window.
// ---------------------------------------------------------------------------
__global__ __launch_bounds__(256)
void fill_b(const int* __restrict__ rs, const uint2* __restrict__ bkt,
            uint2* __restrict__ scv)
{
    __shared__ int cur[RPB_F];
    const int b  = blockIdx.x;
    const int r0 = b << 10;
    const int nr = min(RPB_F, N_ROWS - r0);
    const int t  = threadIdx.x;

    for (int i = t; i < nr; i += 256) cur[i] = rs[r0 + i];
    __syncthreads();

    const int e0 = rs[r0];
    const int e1 = rs[min(r0 + RPB_F, N_ROWS)];
    for (int e = e0 + t; e < e1; e += 256) {
        const uint2 rec = bkt[e];
        const int rl = (int)(rec.x >> 17);
        const int p  = atomicAdd(&cur[rl], 1);
        scv[p] = make_uint2(rec.x & 0x1FFFFu, rec.y);
    }
}

// ---------------------------------------------------------------------------
// 4a) Gather-SPMM vs LDS W (fp32), unroll 8/4/1 for deep MLP.
// ---------------------------------------------------------------------------
__global__ __launch_bounds__(256)
void gather_W(const int* __restrict__ rs, const uint2* __restrict__ scv,
              const float* __restrict__ W, __hip_bfloat16* __restrict__ dst)
{
    __shared__ float Wl[IN_C * OUT_C];
    for (int i = threadIdx.x; i < IN_C * OUT_C; i += blockDim.x) Wl[i] = W[i];
    __syncthreads();

    const int lane = threadIdx.x & 63;
    const int wave = blockIdx.x * 4 + (threadIdx.x >> 6);
    const int nw   = gridDim.x * 4;

    for (int r = wave; r < N_ROWS; r += nw) {
        const int s = rs[r], t = rs[r + 1];
        float a0 = 0.f, a1 = 0.f, a2 = 0.f, a3 = 0.f;
        float a4 = 0.f, a5 = 0.f, a6 = 0.f, a7 = 0.f;
        int j = s;
        for (; j + 7 < t; j += 8) {
            const uint2 p0 = scv[j],     p1 = scv[j + 1];
            const uint2 p2 = scv[j + 2], p3 = scv[j + 3];
            const uint2 p4 = scv[j + 4], p5 = scv[j + 5];
            const uint2 p6 = scv[j + 6], p7 = scv[j + 7];
            a0 += __uint_as_float(p0.y) * Wl[p0.x * OUT_C + lane];
            a1 += __uint_as_float(p1.y) * Wl[p1.x * OUT_C + lane];
            a2 += __uint_as_float(p2.y) * Wl[p2.x * OUT_C + lane];
            a3 += __uint_as_float(p3.y) * Wl[p3.x * OUT_C + lane];
            a4 += __uint_as_float(p4.y) * Wl[p4.x * OUT_C + lane];
            a5 += __uint_as_float(p5.y) * Wl[p5.x * OUT_C + lane];
            a6 += __uint_as_float(p6.y) * Wl[p6.x * OUT_C + lane];
            a7 += __uint_as_float(p7.y) * Wl[p7.x * OUT_C + lane];
        }
        for (; j + 3 < t; j += 4) {
            const uint2 p0 = scv[j],     p1 = scv[j + 1];
            const uint2 p2 = scv[j + 2], p3 = scv[j + 3];
            a0 += __uint_as_float(p0.y) * Wl[p0.x * OUT_C + lane];
            a1 += __uint_as_float(p1.y) * Wl[p1.x * OUT_C + lane];
            a2 += __uint_as_float(p2.y) * Wl[p2.x * OUT_C + lane];
            a3 += __uint_as_float(p3.y) * Wl[p3.x * OUT_C + lane];
        }
        for (; j < t; ++j) {
            const uint2 p = scv[j];
            a0 += __uint_as_float(p.y) * Wl[p.x * OUT_C + lane];
        }
        dst[(size_t)r * OUT_C + lane] =
            __float2bfloat16(((a0 + a1) + (a2 + a3)) + ((a4 + a5) + (a6 + a7)));
    }
}

// ---------------------------------------------------------------------------
// 4b) Gather-SPMM from bf16 src, unroll 8/4/1 (8 independent src gathers
//     in flight). MODE 1: dst[r] = bf16(theta[r]*sum). MODE 2: relu->fp32 out.
// ---------------------------------------------------------------------------
template <int MODE>
__global__ __launch_bounds__(256)
void gather_mat(const int* __restrict__ rs, const uint2* __restrict__ scv,
                const __hip_bfloat16* __restrict__ src,
                const float* __restrict__ theta,
                __hip_bfloat16* __restrict__ dstb,
                float* __restrict__ dstf, int scale)
{
    const int lane = threadIdx.x & 63;
    const int wave = blockIdx.x * 4 + (threadIdx.x >> 6);
    const int nw   = gridDim.x * 4;

    for (int r = wave; r < N_ROWS; r += nw) {
        const int s = rs[r], t = rs[r + 1];
        float a0 = 0.f, a1 = 0.f, a2 = 0.f, a3 = 0.f;
        float a4 = 0.f, a5 = 0.f, a6 = 0.f, a7 = 0.f;
        int j = s;
        for (; j + 7 < t; j += 8) {
            const uint2 p0 = scv[j],     p1 = scv[j + 1];
            const uint2 p2 = scv[j + 2], p3 = scv[j + 3];
            const uint2 p4 = scv[j + 4], p5 = scv[j + 5];
            const uint2 p6 = scv[j + 6], p7 = scv[j + 7];
            const float w0 = bf2f(src[(size_t)p0.x * OUT_C + lane]);
            const float w1 = bf2f(src[(size_t)p1.x * OUT_C + lane]);
            const float w2 = bf2f(src[(size_t)p2.x * OUT_C + lane]);
            const float w3 = bf2f(src[(size_t)p3.x * OUT_C + lane]);
            const float w4 = bf2f(src[(size_t)p4.x * OUT_C + lane]);
            const float w5 = bf2f(src[(size_t)p5.x * OUT_C + lane]);
            const float w6 = bf2f(src[(size_t)p6.x * OUT_C + lane]);
            const float w7 = bf2f(src[(size_t)p7.x * OUT_C + lane]);
            a0 += __uint_as_float(p0.y) * w0;
            a1 += __uint_as_float(p1.y) * w1;
            a2 += __uint_as_float(p2.y) * w2;
            a3 += __uint_as_float(p3.y) * w3;
            a4 += __uint_as_float(p4.y) * w4;
            a5 += __uint_as_float(p5.y) * w5;
            a6 += __uint_as_float(p6.y) * w6;
            a7 += __uint_as_float(p7.y) * w7;
        }
        for (; j + 3 < t; j += 4) {
            const uint2 p0 = scv[j],     p1 = scv[j + 1];
            const uint2 p2 = scv[j + 2], p3 = scv[j + 3];
            const float w0 = bf2f(src[(size_t)p0.x * OUT_C + lane]);
            const float w1 = bf2f(src[(size_t)p1.x * OUT_C + lane]);
            const float w2 = bf2f(src[(size_t)p2.x * OUT_C + lane]);
            const float w3 = bf2f(src[(size_t)p3.x * OUT_C + lane]);
            a0 += __uint_as_float(p0.y) * w0;
            a1 += __uint_as_float(p1.y) * w1;
            a2 += __uint_as_float(p2.y) * w2;
            a3 += __uint_as_float(p3.y) * w3;
        }
        for (; j < t; ++j) {
            const uint2 p = scv[j];
            a0 += __uint_as_float(p.y) * bf2f(src[(size_t)p.x * OUT_C + lane]);
        }
        const float acc = ((a0 + a1) + (a2 + a3)) + ((a4 + a5) + (a6 + a7));
        if (MODE == 1) {
            dstb[(size_t)r * OUT_C + lane] = __float2bfloat16(theta[r] * acc);
        } else {
            dstf[((size_t)r * S_SC + scale) * OUT_C + lane] = acc > 0.0f ? acc : 0.0f;
        }
    }
}

extern "C" void kernel_launch(void* const* d_in, const int* in_sizes, int n_in,
                              void* d_out, int out_size, void* d_ws, size_t ws_size,
                              hipStream_t stream)
{
    const int*   phi_idx  = (const int*)d_in[0];
    const float* phi_val  = (const float*)d_in[1];
    const int*   pinv_idx = (const int*)d_in[2];
    const float* pinv_val = (const float*)d_in[3];
    const int*   fidx     = (const int*)d_in[4];
    const float* fval     = (const float*)d_in[5];
    const float* W        = (const float*)d_in[6];
    const float* theta    = (const float*)d_in[7];
    float*       out      = (float*)d_out;          // (N,S,64) fp32

    // ---- workspace (≈76.4 MB; 76.8 MB proven) ----
    __hip_bfloat16* filtered = (__hip_bfloat16*)d_ws;                  // 12.8 MB
    __hip_bfloat16* z        = filtered + (size_t)N_ROWS * OUT_C;      // 12.8 MB
    uint2* bkt = (uint2*)(z + (size_t)N_ROWS * OUT_C);                 // 12.8 MB
    uint2* scv = bkt + NNZ;                                            // 12.8 MB
    unsigned* counts16 = (unsigned*)(scv + NNZ);                       // 22.4 MB
    int*   rs          = (int*)(counts16 + (size_t)NMAT * NCH * HROWS);// 2.8 MB
    int*   bsum        = rs + (size_t)NMAT * RS_STR;                   // 7 KB
    int*   bucket_cur  = bsum + NMAT * 256;                            // 2.7 KB

    // matrix order: 0=F, per scale i: 1+2i=PhiInv_i, 2+2i=Phi_i
    RowPtrs P;
    P.p[0] = fidx;
    for (int i = 0; i < S_SC; ++i) {
        P.p[1 + 2 * i] = pinv_idx + (size_t)(2 * i) * NNZ;
        P.p[2 + 2 * i] = phi_idx  + (size_t)(2 * i) * NNZ;
    }

    // ---- batched CSR metadata for all 7 matrices ----
    hist_binned<<<dim3(NCH * NBIN_H, NMAT), 512, 0, stream>>>(P, counts16);
    scan_l1<<<dim3(BLKS_SCAN, NMAT), 256, 0, stream>>>(counts16, rs, bsum);
    scan_l2<<<NMAT, 256, 0, stream>>>(bsum);
    finalize<<<(NMAT * N_ROWS + 255) / 256, 256, 0, stream>>>(bsum, rs, bucket_cur);

    // ---- m=0: filtered = bf16(F @ W) ----
    fill_a<<<BLKS_A, 256, 0, stream>>>(fidx, fidx + NNZ, fval, bucket_cur, bkt);
    fill_b<<<NBKT, 256, 0, stream>>>(rs, bkt, scv);
    gather_W<<<2048, 256, 0, stream>>>(rs, scv, W, filtered);

    for (int i = 0; i < S_SC; ++i) {
        const int m1 = 1 + 2 * i, m2 = 2 + 2 * i;
        const int*   zc = pinv_idx + (size_t)(2 * i + 1) * NNZ;
        const float* zv = pinv_val + (size_t)i * NNZ;
        const int*   oc = phi_idx  + (size_t)(2 * i + 1) * NNZ;
        const float* ov = phi_val  + (size_t)i * NNZ;

        // z = bf16(theta ⊙ (PhiInv_i @ filtered))
        fill_a<<<BLKS_A, 256, 0, stream>>>(P.p[m1], zc, zv,
                                           bucket_cur + m1 * NBKT, bkt);
        fill_b<<<NBKT, 256, 0, stream>>>(rs + (size_t)m1 * RS_STR, bkt, scv);
        gather_mat<1><<<4096, 256, 0, stream>>>(rs + (size_t)m1 * RS_STR, scv,
                                                filtered, theta, z, nullptr, 0);

        // out[:, i, :] = relu(Phi_i @ z)
        fill_a<<<BLKS_A, 256, 0, stream>>>(P.p[m2], oc, ov,
                                           bucket_cur + m2 * NBKT, bkt);
        fill_b<<<NBKT, 256, 0, stream>>>(rs + (size_t)m2 * RS_STR, bkt, scv);
        gather_mat<2><<<4096, 256, 0, stream>>>(rs + (size_t)m2 * RS_STR, scv,
                                                z, nullptr, nullptr, out, i);
    }
}

// Round 7
// 1010.684 us; speedup vs baseline: 5.0794x; 1.0100x over previous
//
#include <hip/hip_runtime.h>
#include <hip/hip_bf16.h>

#define N_ROWS 100000
#define IN_C   128
#define OUT_C  64
#define S_SC   3
#define NNZ    1600000
#define NMAT   7

#define NCH    16            // hist chunk-copies (parallelism only)
#define HROWS  (N_ROWS / 2)  // u16-pair words per copy

#define SEG       512
#define BLKS_SCAN 196   // 196*512 = 100352 >= 100000

#define NSEG   (NNZ / 256)   // 6250 256-edge segments
#define RPB    25000         // rows per histogram bin
#define NBIN_H 4             // 4*25000 = 100000 exact

#define RPB_F  1024                          // rows per fill bucket (2^10)
#define NBKT   98                            // ceil(100000/1024)
#define EPB_A  2048                          // edges per pass-A block
#define BLKS_A 782                           // ceil(NNZ/EPB_A)
#define RS_STR (N_ROWS + 1)                  // row_start stride (CSR-style)

#define GH     2048                          // gather blocks per half launch
#define RHALF  50000

struct RowPtrs { const int* p[NMAT]; };

__device__ __forceinline__ float bf2f(__hip_bfloat16 x) { return __bfloat162float(x); }

// ---------------------------------------------------------------------------
// 1) Binned histogram, zero global atomics. 16 chunk-copies, u16 counts.
// ---------------------------------------------------------------------------
__global__ __launch_bounds__(512)
void hist_binned(RowPtrs P, unsigned* __restrict__ counts16)
{
    __shared__ unsigned cnt[RPB / 2];
    const int m    = blockIdx.y;
    const int c    = blockIdx.x & (NCH - 1);
    const int bin0 = (blockIdx.x >> 4) * RPB;
    const int t    = threadIdx.x;

    for (int i = t; i < RPB / 2; i += 512) cnt[i] = 0;
    __syncthreads();

    const int* rows = P.p[m];
    const int wv = t >> 6;
    const int ln = t & 63;

    for (int sg = c + NCH * wv; sg < NSEG; sg += NCH * 8) {
        const int4 v = ((const int4*)rows)[sg * 64 + ln];
        unsigned i0 = (unsigned)(v.x - bin0);
        unsigned i1 = (unsigned)(v.y - bin0);
        unsigned i2 = (unsigned)(v.z - bin0);
        unsigned i3 = (unsigned)(v.w - bin0);
        if (i0 < RPB) atomicAdd(&cnt[i0 >> 1], 1u << ((i0 & 1) * 16));
        if (i1 < RPB) atomicAdd(&cnt[i1 >> 1], 1u << ((i1 & 1) * 16));
        if (i2 < RPB) atomicAdd(&cnt[i2 >> 1], 1u << ((i2 & 1) * 16));
        if (i3 < RPB) atomicAdd(&cnt[i3 >> 1], 1u << ((i3 & 1) * 16));
    }
    __syncthreads();

    unsigned* dst = counts16 + ((size_t)m * NCH + c) * HROWS + (bin0 >> 1);
    for (int i = t; i < RPB / 2; i += 512) dst[i] = cnt[i];
}

// ---------------------------------------------------------------------------
// 2a) Per-512-row block scan of totals (sum over 16 u16 copies) + block sums
// ---------------------------------------------------------------------------
__global__ __launch_bounds__(256)
void scan_l1(const unsigned* __restrict__ counts16, int* __restrict__ rs,
             int* __restrict__ bsum)
{
    __shared__ int buf[2][SEG];
    const int m   = blockIdx.y;
    const int blk = blockIdx.x;
    const int t   = threadIdx.x;
    const unsigned* cnt = counts16 + (size_t)m * NCH * HROWS;

    for (int k = t; k < SEG; k += 256) {
        const int g = blk * SEG + k;
        int tot = 0;
        if (g < N_ROWS) {
            const int wi = g >> 1, sh = (g & 1) * 16;
            for (int c = 0; c < NCH; ++c)
                tot += (int)((cnt[(size_t)c * HROWS + wi] >> sh) & 0xffffu);
        }
        buf[0][k] = tot;
    }
    __syncthreads();

    int src = 0;
    for (int off = 1; off < SEG; off <<= 1) {
        for (int k = t; k < SEG; k += 256) {
            int v = buf[src][k];
            if (k >= off) v += buf[src][k - off];
            buf[1 - src][k] = v;
        }
        src ^= 1;
        __syncthreads();
    }
    for (int k = t; k < SEG; k += 256) {
        const int g = blk * SEG + k;
        if (g < N_ROWS)
            rs[(size_t)m * RS_STR + g] = (k == 0) ? 0 : buf[src][k - 1];
    }
    if (t == 0) bsum[m * 256 + blk] = buf[src][SEG - 1];
}

// ---------------------------------------------------------------------------
// 2b) Exclusive scan of block sums; one block per matrix
// ---------------------------------------------------------------------------
__global__ __launch_bounds__(256)
void scan_l2(int* __restrict__ bsum)
{
    __shared__ int buf[2][256];
    const int t = threadIdx.x;
    int* b = bsum + blockIdx.x * 256;
    buf[0][t] = (t < BLKS_SCAN) ? b[t] : 0;
    __syncthreads();
    int src = 0;
    for (int off = 1; off < 256; off <<= 1) {
        int v = buf[src][t];
        if (t >= off) v += buf[src][t - off];
        buf[1 - src][t] = v;
        src ^= 1;
        __syncthreads();
    }
    if (t < BLKS_SCAN) b[t] = (t == 0) ? 0 : buf[src][t - 1];
}

// ---------------------------------------------------------------------------
// 2c) Finalize: absolute row starts; bucket cursors; terminal NNZ sentinel
// ---------------------------------------------------------------------------
__global__ __launch_bounds__(256)
void finalize(const int* __restrict__ bsum, int* __restrict__ rs,
              int* __restrict__ bucket_cur)
{
    const int i = blockIdx.x * 256 + threadIdx.x;
    if (i >= NMAT * N_ROWS) return;
    const int m = i / N_ROWS;
    const int r = i - m * N_ROWS;
    const size_t ri = (size_t)m * RS_STR + r;
    const int base = rs[ri] + bsum[m * 256 + r / SEG];
    rs[ri] = base;
    if ((r & (RPB_F - 1)) == 0) bucket_cur[m * NBKT + (r >> 10)] = base;
    if (r == 0) rs[(size_t)m * RS_STR + N_ROWS] = NNZ;
}

// ---------------------------------------------------------------------------
// fill_a body: bucket scatter (LDS reorder, 98 reservation atomics/block)
// ---------------------------------------------------------------------------
struct FaLds {
    int cnt[NBKT], lofs[NBKT], lcur[NBKT], gbase[NBKT];
    uint2 stg[EPB_A];
    int gpos[EPB_A];
};

__device__ __forceinline__ void fill_a_body(FaLds& L, int blk,
    const int* __restrict__ rows, const int* __restrict__ cols,
    const float* __restrict__ vals, int* __restrict__ bcur,
    uint2* __restrict__ bkt)
{
    const int t  = threadIdx.x;
    const int e0 = blk * EPB_A;
    const int n  = min(EPB_A, NNZ - e0);

    for (int b = t; b < NBKT; b += 256) L.cnt[b] = 0;
    __syncthreads();

    int rr[8], cc[8], bb[8]; unsigned vv[8];
    #pragma unroll
    for (int k = 0; k < 8; ++k) {
        const int idx = t + k * 256;
        if (idx < n) {
            const int e = e0 + idx;
            rr[k] = rows[e];
            cc[k] = cols[e];
            vv[k] = __float_as_uint(vals[e]);
            bb[k] = rr[k] >> 10;
            atomicAdd(&L.cnt[bb[k]], 1);
        } else bb[k] = -1;
    }
    __syncthreads();

    if (t == 0) {
        int run = 0;
        for (int b = 0; b < NBKT; ++b) { L.lofs[b] = run; run += L.cnt[b]; }
    }
    __syncthreads();
    if (t < NBKT) {
        L.gbase[t] = atomicAdd(&bcur[t], L.cnt[t]);
        L.lcur[t]  = L.lofs[t];
    }
    __syncthreads();

    #pragma unroll
    for (int k = 0; k < 8; ++k) {
        if (bb[k] >= 0) {
            const int p = atomicAdd(&L.lcur[bb[k]], 1);
            L.stg[p]  = make_uint2(((unsigned)(rr[k] & (RPB_F - 1)) << 17) |
                                   (unsigned)cc[k], vv[k]);
            L.gpos[p] = L.gbase[bb[k]] + (p - L.lofs[bb[k]]);
        }
    }
    __syncthreads();

    for (int p = t; p < n; p += 256) bkt[L.gpos[p]] = L.stg[p];
}

// ---------------------------------------------------------------------------
// fill_b body: per-bucket fill with private LDS cursors
// ---------------------------------------------------------------------------
__device__ __forceinline__ void fill_b_body(int* cur, int b,
    const int* __restrict__ rs_m, const uint2* __restrict__ bkt,
    uint2* __restrict__ scv)
{
    const int r0 = b << 10;
    const int nr = min(RPB_F, N_ROWS - r0);
    const int t  = threadIdx.x;

    for (int i = t; i < nr; i += 256) cur[i] = rs_m[r0 + i];
    __syncthreads();

    const int e0 = rs_m[r0];
    const int e1 = rs_m[min(r0 + RPB_F, N_ROWS)];
    for (int e = e0 + t; e < e1; e += 256) {
        const uint2 rec = bkt[e];
        const int rl = (int)(rec.x >> 17);
        const int p  = atomicAdd(&cur[rl], 1);
        scv[p] = make_uint2(rec.x & 0x1FFFFu, rec.y);
    }
}

// ---------------------------------------------------------------------------
// standalone fill kernels (used for matrix 0 head)
// ---------------------------------------------------------------------------
__global__ __launch_bounds__(256)
void fill_a(const int* __restrict__ rows, const int* __restrict__ cols,
            const float* __restrict__ vals, int* __restrict__ bcur,
            uint2* __restrict__ bkt)
{
    __shared__ FaLds L;
    fill_a_body(L, blockIdx.x, rows, cols, vals, bcur, bkt);
}

__global__ __launch_bounds__(256)
void fill_b(const int* __restrict__ rs_m, const uint2* __restrict__ bkt,
            uint2* __restrict__ scv)
{
    __shared__ int cur[RPB_F];
    fill_b_body(cur, blockIdx.x, rs_m, bkt, scv);
}

// ---------------------------------------------------------------------------
// gather body, unroll 8/4/1.
// GMODE 0: src = LDS fp32 W -> bf16 dst.  GMODE 1: bf16 src * theta -> bf16.
// GMODE 2: bf16 src, relu -> fp32 out[:,sc,:].
// ---------------------------------------------------------------------------
template <int GMODE>
__device__ __forceinline__ float fetch_src(const float* Wl,
                                           const __hip_bfloat16* src,
                                           unsigned cx, int lane)
{
    if constexpr (GMODE == 0) return Wl[cx * OUT_C + lane];
    else return bf2f(src[(size_t)cx * OUT_C + lane]);
}

template <int GMODE>
__device__ __forceinline__ void gather_body(const float* Wl,
    const int* __restrict__ rs_m, const uint2* __restrict__ scv,
    const void* __restrict__ srcv, const float* __restrict__ theta,
    __hip_bfloat16* __restrict__ dstb, float* __restrict__ dstf,
    int scale, int r0, int r1, int wave, int nw, int lane)
{
    const __hip_bfloat16* src = (const __hip_bfloat16*)srcv;

    for (int r = r0 + wave; r < r1; r += nw) {
        const int s = rs_m[r], t = rs_m[r + 1];
        float a0 = 0.f, a1 = 0.f, a2 = 0.f, a3 = 0.f;
        float a4 = 0.f, a5 = 0.f, a6 = 0.f, a7 = 0.f;
        int j = s;
        for (; j + 7 < t; j += 8) {
            const uint2 p0 = scv[j],     p1 = scv[j + 1];
            const uint2 p2 = scv[j + 2], p3 = scv[j + 3];
            const uint2 p4 = scv[j + 4], p5 = scv[j + 5];
            const uint2 p6 = scv[j + 6], p7 = scv[j + 7];
            const float w0 = fetch_src<GMODE>(Wl, src, p0.x, lane);
            const float w1 = fetch_src<GMODE>(Wl, src, p1.x, lane);
            const float w2 = fetch_src<GMODE>(Wl, src, p2.x, lane);
            const float w3 = fetch_src<GMODE>(Wl, src, p3.x, lane);
            const float w4 = fetch_src<GMODE>(Wl, src, p4.x, lane);
            const float w5 = fetch_src<GMODE>(Wl, src, p5.x, lane);
            const float w6 = fetch_src<GMODE>(Wl, src, p6.x, lane);
            const float w7 = fetch_src<GMODE>(Wl, src, p7.x, lane);
            a0 += __uint_as_float(p0.y) * w0;
            a1 += __uint_as_float(p1.y) * w1;
            a2 += __uint_as_float(p2.y) * w2;
            a3 += __uint_as_float(p3.y) * w3;
            a4 += __uint_as_float(p4.y) * w4;
            a5 += __uint_as_float(p5.y) * w5;
            a6 += __uint_as_float(p6.y) * w6;
            a7 += __uint_as_float(p7.y) * w7;
        }
        for (; j + 3 < t; j += 4) {
            const uint2 p0 = scv[j],     p1 = scv[j + 1];
            const uint2 p2 = scv[j + 2], p3 = scv[j + 3];
            const float w0 = fetch_src<GMODE>(Wl, src, p0.x, lane);
            const float w1 = fetch_src<GMODE>(Wl, src, p1.x, lane);
            const float w2 = fetch_src<GMODE>(Wl, src, p2.x, lane);
            const float w3 = fetch_src<GMODE>(Wl, src, p3.x, lane);
            a0 += __uint_as_float(p0.y) * w0;
            a1 += __uint_as_float(p1.y) * w1;
            a2 += __uint_as_float(p2.y) * w2;
            a3 += __uint_as_float(p3.y) * w3;
        }
        for (; j < t; ++j) {
            const uint2 p = scv[j];
            a0 += __uint_as_float(p.y) * fetch_src<GMODE>(Wl, src, p.x, lane);
        }
        const float acc = ((a0 + a1) + (a2 + a3)) + ((a4 + a5) + (a6 + a7));
        if (GMODE == 0) {
            dstb[(size_t)r * OUT_C + lane] = __float2bfloat16(acc);
        } else if (GMODE == 1) {
            dstb[(size_t)r * OUT_C + lane] = __float2bfloat16(theta[r] * acc);
        } else {
            dstf[((size_t)r * S_SC + scale) * OUT_C + lane] = acc > 0.0f ? acc : 0.0f;
        }
    }
}

// ---------------------------------------------------------------------------
// Fused launch: blocks [0,nFill) do fill work (kind 1 = fill_a, 2 = fill_b)
// for the NEXT matrix; blocks [nFill, nFill+GH) gather rows [r0,r1) of the
// CURRENT matrix. Fill blocks first so they dispatch immediately.
// ---------------------------------------------------------------------------
template <int GMODE>
__global__ __launch_bounds__(256)
void fused_gf(int nFill, int fillKind,
              const int* faRows, const int* faCols, const float* faVals,
              int* faBcur,
              const int* fbRs, uint2* bkt, uint2* fbScv,
              const int* gRs, const uint2* gScv, const void* gSrc,
              const float* theta, __hip_bfloat16* dstb, float* dstf,
              int scale, int r0, int r1)
{
    constexpr int WLN = (GMODE == 0) ? (IN_C * OUT_C) : 1;
    __shared__ union ULds {
        FaLds fa;
        int   fbcur[RPB_F];
        float Wl[WLN];
    } u;

    const int t = threadIdx.x;
    if ((int)blockIdx.x < nFill) {
        if (fillKind == 1)
            fill_a_body(u.fa, blockIdx.x, faRows, faCols, faVals, faBcur, bkt);
        else
            fill_b_body(u.fbcur, blockIdx.x, fbRs, bkt, fbScv);
        return;
    }

    const int gb   = (int)blockIdx.x - nFill;
    const int lane = t & 63;
    const int wave = gb * 4 + (t >> 6);
    const int nw   = ((int)gridDim.x - nFill) * 4;

    const float* Wl = nullptr;
    if constexpr (GMODE == 0) {
        const float* W = (const float*)gSrc;
        for (int i = t; i < IN_C * OUT_C; i += 256) u.Wl[i] = W[i];
        __syncthreads();
        Wl = u.Wl;
    }
    gather_body<GMODE>(Wl, gRs, gScv, gSrc, theta, dstb, dstf,
                       scale, r0, r1, wave, nw, lane);
}

// ---------------------------------------------------------------------------
extern "C" void kernel_launch(void* const* d_in, const int* in_sizes, int n_in,
                              void* d_out, int out_size, void* d_ws, size_t ws_size,
                              hipStream_t stream)
{
    const int*   phi_idx  = (const int*)d_in[0];
    const float* phi_val  = (const float*)d_in[1];
    const int*   pinv_idx = (const int*)d_in[2];
    const float* pinv_val = (const float*)d_in[3];
    const int*   fidx     = (const int*)d_in[4];
    const float* fval     = (const float*)d_in[5];
    const float* W        = (const float*)d_in[6];
    const float* theta    = (const float*)d_in[7];
    float*       out      = (float*)d_out;          // (N,S,64) fp32

    // ---- workspace (≈76.4 MB; 76.8 MB proven) ----
    __hip_bfloat16* filtered = (__hip_bfloat16*)d_ws;                  // 12.8 MB
    __hip_bfloat16* z        = filtered + (size_t)N_ROWS * OUT_C;      // 12.8 MB
    uint2* bkt  = (uint2*)(z + (size_t)N_ROWS * OUT_C);                // 12.8 MB
    uint2* scv0 = bkt + NNZ;                                           // 12.8 MB
    unsigned* counts16 = (unsigned*)(scv0 + NNZ);                      // 22.4 MB
    uint2* scv1 = (uint2*)counts16;     // overlay: counts16 dead after scan_l1
    int*   rs         = (int*)(counts16 + (size_t)NMAT * NCH * HROWS); // 2.8 MB
    int*   bsum       = rs + (size_t)NMAT * RS_STR;                    // 7 KB
    int*   bucket_cur = bsum + NMAT * 256;                             // 2.7 KB

    // matrix order k: 0=F, per scale i: 1+2i=PhiInv_i, 2+2i=Phi_i
    RowPtrs P;
    const int* kRows[NMAT]; const int* kCols[NMAT]; const float* kVals[NMAT];
    kRows[0] = fidx; kCols[0] = fidx + NNZ; kVals[0] = fval;
    for (int i = 0; i < S_SC; ++i) {
        kRows[1 + 2 * i] = pinv_idx + (size_t)(2 * i) * NNZ;
        kCols[1 + 2 * i] = pinv_idx + (size_t)(2 * i + 1) * NNZ;
        kVals[1 + 2 * i] = pinv_val + (size_t)i * NNZ;
        kRows[2 + 2 * i] = phi_idx + (size_t)(2 * i) * NNZ;
        kCols[2 + 2 * i] = phi_idx + (size_t)(2 * i + 1) * NNZ;
        kVals[2 + 2 * i] = phi_val + (size_t)i * NNZ;
    }
    for (int k = 0; k < NMAT; ++k) P.p[k] = kRows[k];

    // ---- batched CSR metadata for all 7 matrices ----
    hist_binned<<<dim3(NCH * NBIN_H, NMAT), 512, 0, stream>>>(P, counts16);
    scan_l1<<<dim3(BLKS_SCAN, NMAT), 256, 0, stream>>>(counts16, rs, bsum);
    scan_l2<<<NMAT, 256, 0, stream>>>(bsum);
    finalize<<<(NMAT * N_ROWS + 255) / 256, 256, 0, stream>>>(bsum, rs, bucket_cur);

    // ---- head: fill matrix 0 ----
    fill_a<<<BLKS_A, 256, 0, stream>>>(kRows[0], kCols[0], kVals[0],
                                       bucket_cur, bkt);
    fill_b<<<NBKT, 256, 0, stream>>>(rs, bkt, scv0);

    // ---- pipelined gather(k) || fill(k+1) ----
    for (int k = 0; k < NMAT; ++k) {
        const uint2* gs   = (k & 1) ? scv1 : scv0;
        const int*   grs  = rs + (size_t)k * RS_STR;
        const void*  gsrc = (k == 0) ? (const void*)W
                          : (k & 1)  ? (const void*)filtered : (const void*)z;
        __hip_bfloat16* db = (k == 0) ? filtered : ((k & 1) ? z : nullptr);
        const bool isOut = (k >= 2) && !(k & 1);
        float* df = isOut ? out : nullptr;
        const int sc = isOut ? (k - 2) / 2 : 0;
        const int gm = (k == 0) ? 0 : ((k & 1) ? 1 : 2);

        const int  kn      = k + 1;
        const bool hasNext = kn < NMAT;
        uint2* ns = (kn & 1) ? scv1 : scv0;

        const int nFa = hasNext ? BLKS_A : 0;
        const int nFb = hasNext ? NBKT : 0;

        // half 1: gather rows [0,RHALF) || fill_a(k+1)
        switch (gm) {
        case 0: fused_gf<0><<<nFa + GH, 256, 0, stream>>>(nFa, 1,
                    hasNext ? kRows[kn] : nullptr, hasNext ? kCols[kn] : nullptr,
                    hasNext ? kVals[kn] : nullptr,
                    hasNext ? bucket_cur + kn * NBKT : nullptr,
                    nullptr, bkt, nullptr,
                    grs, gs, gsrc, theta, db, df, sc, 0, RHALF); break;
        case 1: fused_gf<1><<<nFa + GH, 256, 0, stream>>>(nFa, 1,
                    hasNext ? kRows[kn] : nullptr, hasNext ? kCols[kn] : nullptr,
                    hasNext ? kVals[kn] : nullptr,
                    hasNext ? bucket_cur + kn * NBKT : nullptr,
                    nullptr, bkt, nullptr,
                    grs, gs, gsrc, theta, db, df, sc, 0, RHALF); break;
        default: fused_gf<2><<<nFa + GH, 256, 0, stream>>>(nFa, 1,
                    hasNext ? kRows[kn] : nullptr, hasNext ? kCols[kn] : nullptr,
                    hasNext ? kVals[kn] : nullptr,
                    hasNext ? bucket_cur + kn * NBKT : nullptr,
                    nullptr, bkt, nullptr,
                    grs, gs, gsrc, theta, db, df, sc, 0, RHALF); break;
        }
        // half 2: gather rows [RHALF,N) || fill_b(k+1)
        switch (gm) {
        case 0: fused_gf<0><<<nFb + GH, 256, 0, stream>>>(nFb, 2,
                    nullptr, nullptr, nullptr, nullptr,
                    hasNext ? rs + (size_t)kn * RS_STR : nullptr, bkt,
                    hasNext ? ns : nullptr,
                    grs, gs, gsrc, theta, db, df, sc, RHALF, N_ROWS); break;
        case 1: fused_gf<1><<<nFb + GH, 256, 0, stream>>>(nFb, 2,
                    nullptr, nullptr, nullptr, nullptr,
                    hasNext ? rs + (size_t)kn * RS_STR : nullptr, bkt,
                    hasNext ? ns : nullptr,
                    grs, gs, gsrc, theta, db, df, sc, RHALF, N_ROWS); break;
        default: fused_gf<2><<<nFb + GH, 256, 0, stream>>>(nFb, 2,
                    nullptr, nullptr, nullptr, nullptr,
                    hasNext ? rs + (size_t)kn * RS_STR : nullptr, bkt,
                    hasNext ? ns : nullptr,
                    grs, gs, gsrc, theta, db, df, sc, RHALF, N_ROWS); break;
        }
    }
}